// Round 7
// baseline (295.664 us; speedup 1.0000x reference)
//
#include <hip/hip_runtime.h>
#include <hip/hip_bf16.h>
#include <hip/hip_fp16.h>

// Problem constants (from reference file)
#define N_USERS 50000
#define N_NODES 100000
#define N_EDGES 1600000
#define DIM 128
#define CAP 64            // per-row bucket capacity (max degree ~45 for Poisson(16))

// fused kernel: blocks 0..GEMM_BLOCKS-1 do the MFMA gemm (no LDS, <=64 VGPR),
// remaining blocks do bucket fill, 1 edge/thread (R5 showed 4 edges/thread
// regresses). Low footprint => 8 blocks/CU so fill runs at high concurrency.
#define GEMM_BLOCKS 1024
#define FILL_BLOCKS (N_EDGES / 256)            // 6250, exact
#define FUSED_GRID (GEMM_BLOCKS + FILL_BLOCKS)

typedef __attribute__((ext_vector_type(8))) _Float16 half8;
typedef __attribute__((ext_vector_type(4))) _Float16 half4;
typedef __attribute__((ext_vector_type(4))) float f32x4;

// ---------------- prep: zero counts + swizzle W into B-fragment layout -----
// wswz[((t*4+s)*64+lane)*8+j] = W[s*32+(lane>>4)*8+j][t*16+(lane&15)]  (f16)
// 32 KB total -> stays L2/L3 resident; gemm loads fragments from global.
__global__ __launch_bounds__(256) void prep_kernel(
        const float* __restrict__ W, int* __restrict__ counts,
        _Float16* __restrict__ wswz, int do_counts) {
    const int i = blockIdx.x * blockDim.x + threadIdx.x;
    if (do_counts && i < N_NODES / 4) ((int4*)counts)[i] = (int4){0, 0, 0, 0};
    if (i < DIM * DIM) {
        const int j  = i & 7;
        const int ln = (i >> 3) & 63;
        const int ts = i >> 9;        // 0..31
        const int t  = ts >> 2;
        const int s  = ts & 3;
        const int krow = s * 32 + (ln >> 4) * 8 + j;
        const int col  = t * 16 + (ln & 15);
        wswz[i] = (_Float16)W[krow * DIM + col];
    }
}

// ---------------- gemm body: 16 rows x 64 cols per wave, no LDS ------------
// 16x16x32 f16 MFMA; A-frag: lane holds A[m=lane&15][k=(lane>>4)*8+j];
// C/D: col=lane&15, row=(lane>>4)*4+reg  [verified mapping, learn_hip m89].
// B-fragments read from global wswz (coalesced 1KB per fragment, L2-hot).
__device__ __forceinline__ void gemm_body(
        const float* __restrict__ u_f, const float* __restrict__ v_f,
        const _Float16* __restrict__ wswz, _Float16* __restrict__ node_f,
        int blockId, int nBlocks) {
    const int tid  = threadIdx.x;
    const int lane = tid & 63;
    const int wave = tid >> 6;
    const int m    = lane & 15;
    const int quad = lane >> 4;
    const int n_jobs = (N_NODES / 16) * 2;   // 12500: row-tile x col-half

    for (int w = blockId * 4 + wave; w < n_jobs; w += nBlocks * 4) {
        const int wt = w >> 1;        // row tile (16 rows)
        const int h  = w & 1;         // column half (64 cols)
        const int row = wt * 16 + m;
        const float* src = (row < N_USERS) ? u_f + (size_t)row * DIM
                                           : v_f + (size_t)(row - N_USERS) * DIM;
        f32x4 acc[4];
        #pragma unroll
        for (int t = 0; t < 4; ++t) acc[t] = (f32x4){0.f, 0.f, 0.f, 0.f};

        #pragma unroll
        for (int s = 0; s < 4; ++s) {
            const float* ap = src + s * 32 + quad * 8;
            const float4 a0 = *(const float4*)ap;
            const float4 a1 = *(const float4*)(ap + 4);
            half8 af;
            af[0] = (_Float16)a0.x; af[1] = (_Float16)a0.y;
            af[2] = (_Float16)a0.z; af[3] = (_Float16)a0.w;
            af[4] = (_Float16)a1.x; af[5] = (_Float16)a1.y;
            af[6] = (_Float16)a1.z; af[7] = (_Float16)a1.w;
            #pragma unroll
            for (int t = 0; t < 4; ++t) {
                const int tt = h * 4 + t;
                const half8 wf = *(const half8*)&wswz[((tt * 4 + s) * 64 + lane) * 8];
                acc[t] = __builtin_amdgcn_mfma_f32_16x16x32_f16(af, wf, acc[t], 0, 0, 0);
            }
        }

        const int base = wt * 16;
        #pragma unroll
        for (int t = 0; t < 4; ++t) {
            #pragma unroll
            for (int r = 0; r < 4; ++r) {
                const int orow = base + quad * 4 + r;
                node_f[(size_t)orow * DIM + (h * 4 + t) * 16 + m] = (_Float16)acc[t][r];
            }
        }
    }
}

// ---------------- fused: gemm (blocks 0..1023) + bucket fill ---------------
// gemm and fill are data-independent; fusing lets fill's latency-bound
// scattered atomics hide the gemm (single stream => no overlap otherwise).
// No __shared__ and <=64 VGPR so fill blocks pack 8/CU.
__global__ __launch_bounds__(256, 8) void fused_gemm_fill_kernel(
        const float* __restrict__ u_f, const float* __restrict__ v_f,
        const _Float16* __restrict__ wswz, _Float16* __restrict__ node_f,
        const int* __restrict__ rows, const int* __restrict__ cols,
        const float* __restrict__ vals,
        int* __restrict__ counts, long long* __restrict__ buckets) {
    if (blockIdx.x < GEMM_BLOCKS) {
        gemm_body(u_f, v_f, wswz, node_f, blockIdx.x, GEMM_BLOCKS);
        return;
    }
    const int e = (blockIdx.x - GEMM_BLOCKS) * 256 + threadIdx.x;  // < N_EDGES exact
    const int r = rows[e];
    const int slot = atomicAdd(&counts[r], 1);
    if (slot < CAP) {
        const long long packed =
            ((long long)__float_as_int(vals[e]) << 32) | (unsigned)cols[e];
        buckets[(size_t)r * CAP + slot] = packed;   // plain store: let L2 merge
    }
}

// standalone gemm for the fallback path
__global__ __launch_bounds__(256, 8) void gemm_mfma_kernel(
        const float* __restrict__ u_f, const float* __restrict__ v_f,
        const _Float16* __restrict__ wswz, _Float16* __restrict__ node_f) {
    gemm_body(u_f, v_f, wswz, node_f, blockIdx.x, gridDim.x);
}

// ---------------- gather: one wave per output row, pair-wise edges --------
// lanes 0..31 serve edge j, lanes 32..63 serve edge j+1 (per-lane shfl src);
// each lane loads 4 f16 (8B) of its edge's node_f row. Final shfl_xor(32)
// merges the two half-wave partials. 8-edge unroll -> 4 loads in flight.
__global__ __launch_bounds__(256) void gather_kernel(
        const _Float16* __restrict__ node_f, const int* __restrict__ counts,
        const long long* __restrict__ buckets, float* __restrict__ out) {
    const int row  = (blockIdx.x * blockDim.x + threadIdx.x) >> 6;
    const int lane = threadIdx.x & 63;
    if (row >= N_NODES) return;
    const int pid = lane >> 5;          // which edge of the pair
    const int cl  = lane & 31;          // col-group: cols [cl*4, cl*4+4)

    int cnt = counts[row];
    if (cnt > CAP) cnt = CAP;

    int   col = 0;
    float val = 0.f;
    if (lane < cnt) {
        const long long p = buckets[(size_t)row * CAP + lane];  // coalesced 512B/wave
        col = (int)(unsigned)p;
        val = __int_as_float((int)(p >> 32));
    }

    f32x4 acc = {0.f, 0.f, 0.f, 0.f};
    int j = 0;
    for (; j + 8 <= cnt; j += 8) {                 // wave-uniform trip count
        int c[4]; float v[4]; half4 h[4];
        #pragma unroll
        for (int p = 0; p < 4; ++p) {
            c[p] = __shfl(col, j + 2 * p + pid, 64);
            v[p] = __shfl(val, j + 2 * p + pid, 64);
        }
        #pragma unroll
        for (int p = 0; p < 4; ++p)
            h[p] = *(const half4*)&node_f[(size_t)c[p] * DIM + cl * 4];
        #pragma unroll
        for (int p = 0; p < 4; ++p) {
            acc[0] += v[p] * (float)h[p][0];
            acc[1] += v[p] * (float)h[p][1];
            acc[2] += v[p] * (float)h[p][2];
            acc[3] += v[p] * (float)h[p][3];
        }
    }
    for (; j + 2 <= cnt; j += 2) {
        const int   c = __shfl(col, j + pid, 64);
        const float v = __shfl(val, j + pid, 64);
        const half4 h = *(const half4*)&node_f[(size_t)c * DIM + cl * 4];
        acc[0] += v * (float)h[0];
        acc[1] += v * (float)h[1];
        acc[2] += v * (float)h[2];
        acc[3] += v * (float)h[3];
    }
    if (j < cnt) {                                  // odd edge: lower half only
        const int   c = __shfl(col, j, 64);
        const float vv = __shfl(val, j, 64);
        const float v = pid ? 0.f : vv;
        const half4 h = *(const half4*)&node_f[(size_t)c * DIM + cl * 4];
        acc[0] += v * (float)h[0];
        acc[1] += v * (float)h[1];
        acc[2] += v * (float)h[2];
        acc[3] += v * (float)h[3];
    }

    // merge half-wave partials
    #pragma unroll
    for (int i = 0; i < 4; ++i) acc[i] += __shfl_xor(acc[i], 32, 64);

    if (pid == 0) {                                 // lanes 0..31 store 16B
        f32x4 r;
        r[0] = acc[0] > 0.f ? acc[0] : 0.f;         // fused relu
        r[1] = acc[1] > 0.f ? acc[1] : 0.f;
        r[2] = acc[2] > 0.f ? acc[2] : 0.f;
        r[3] = acc[3] > 0.f ? acc[3] : 0.f;
        // nt store: out is never re-read; keep 50MB out of L2
        __builtin_nontemporal_store(r, (f32x4*)&out[(size_t)row * DIM + cl * 4]);
    }
}

// ---------------- fallback path (small workspace): atomic scatter ----------
__global__ void zero_out_kernel(float* __restrict__ out) {
    int i = blockIdx.x * blockDim.x + threadIdx.x;
    int idx = i * 4;
    if (idx < N_NODES * DIM) {
        float4 z = {0.f, 0.f, 0.f, 0.f};
        *(float4*)&out[idx] = z;
    }
}

__global__ void scatter_kernel(const _Float16* __restrict__ node_f,
                               const int* __restrict__ rows, const int* __restrict__ cols,
                               const float* __restrict__ vals, float* __restrict__ out) {
    int t = blockIdx.x * blockDim.x + threadIdx.x;
    int e = t >> 5;             // 32 threads per edge, 4 elems each
    int part = t & 31;
    if (e >= N_EDGES) return;
    int r = rows[e], c = cols[e];
    float v = vals[e];
    const __half2 h0 = *(const __half2*)&node_f[(size_t)c * DIM + part * 4];
    const __half2 h1 = *(const __half2*)&node_f[(size_t)c * DIM + part * 4 + 2];
    const float2 f0 = __half22float2(h0);
    const float2 f1 = __half22float2(h1);
    float* dst = &out[(size_t)r * DIM + part * 4];
    unsafeAtomicAdd(dst + 0, v * f0.x);
    unsafeAtomicAdd(dst + 1, v * f0.y);
    unsafeAtomicAdd(dst + 2, v * f1.x);
    unsafeAtomicAdd(dst + 3, v * f1.y);
}

__global__ void relu_kernel(float* __restrict__ out) {
    int i = blockIdx.x * blockDim.x + threadIdx.x;
    int idx = i * 4;
    if (idx < N_NODES * DIM) {
        float4 v = *(float4*)&out[idx];
        v.x = v.x > 0.f ? v.x : 0.f;
        v.y = v.y > 0.f ? v.y : 0.f;
        v.z = v.z > 0.f ? v.z : 0.f;
        v.w = v.w > 0.f ? v.w : 0.f;
        *(float4*)&out[idx] = v;
    }
}

extern "C" void kernel_launch(void* const* d_in, const int* in_sizes, int n_in,
                              void* d_out, int out_size, void* d_ws, size_t ws_size,
                              hipStream_t stream) {
    const float* u_f  = (const float*)d_in[0];
    const float* v_f  = (const float*)d_in[1];
    const int*   rows = (const int*)d_in[2];
    const int*   cols = (const int*)d_in[3];
    const float* vals = (const float*)d_in[4];
    const float* W    = (const float*)d_in[5];
    float* out = (float*)d_out;

    char* ws = (char*)d_ws;
    const size_t nodef_bytes  = (size_t)N_NODES * DIM * 2;   // 25,600,000 (f16)
    const size_t counts_bytes = (size_t)N_NODES * 4;         //    400,000
    const size_t bucket_bytes = (size_t)N_NODES * CAP * 8;   // 51,200,000
    const size_t wswz_bytes   = (size_t)DIM * DIM * 2;       //     32,768

    _Float16* node_f = (_Float16*)ws;
    int* counts = (int*)(ws + nodef_bytes);
    long long* buckets = (long long*)(ws + nodef_bytes + counts_bytes);
    _Float16* wswz = (_Float16*)(ws + nodef_bytes + counts_bytes + bucket_bytes);

    if (ws_size >= nodef_bytes + counts_bytes + bucket_bytes + wswz_bytes) {
        prep_kernel<<<(N_NODES / 4 + 255) / 256, 256, 0, stream>>>(W, counts, wswz, 1);
        fused_gemm_fill_kernel<<<FUSED_GRID, 256, 0, stream>>>(
            u_f, v_f, wswz, node_f, rows, cols, vals, counts, buckets);
        gather_kernel<<<(N_NODES * 64 + 255) / 256, 256, 0, stream>>>(
            node_f, counts, buckets, out);
    } else {
        // fallback: atomic scatter (layout: node_f | wswz)
        _Float16* wswz_fb = (_Float16*)(ws + nodef_bytes);
        prep_kernel<<<(DIM * DIM + 255) / 256, 256, 0, stream>>>(W, nullptr, wswz_fb, 0);
        gemm_mfma_kernel<<<1024, 256, 0, stream>>>(u_f, v_f, wswz_fb, node_f);
        zero_out_kernel<<<(N_NODES * DIM / 4 + 255) / 256, 256, 0, stream>>>(out);
        scatter_kernel<<<((size_t)N_EDGES * 32 + 255) / 256, 256, 0, stream>>>(
            node_f, rows, cols, vals, out);
        relu_kernel<<<(N_NODES * DIM / 4 + 255) / 256, 256, 0, stream>>>(out);
    }
}

// Round 8
// 275.106 us; speedup vs baseline: 1.0747x; 1.0747x over previous
//
#include <hip/hip_runtime.h>
#include <hip/hip_bf16.h>
#include <hip/hip_fp16.h>

// Problem constants (from reference file)
#define N_USERS 50000
#define N_NODES 100000
#define N_EDGES 1600000
#define DIM 128
#define CAP 64            // per-row bucket capacity (max degree ~45 for Poisson(16))

// fused kernel (R6 shape — best measured): blocks 0..511 gemm w/ LDS wfrag,
// blocks 512.. bucket fill at 1 edge/thread. R5 (4 edges/thread) and R7
// (no-LDS gemm + high occupancy) both regressed: fill is memory-side
// atomic/line-throughput bound, gemm needs its registers.
#define GEMM_BLOCKS 512
#define FILL_BLOCKS (N_EDGES / 256)            // 6250, exact
#define FUSED_GRID (GEMM_BLOCKS + FILL_BLOCKS)

typedef __attribute__((ext_vector_type(8))) _Float16 half8;
typedef __attribute__((ext_vector_type(4))) _Float16 half4;
typedef __attribute__((ext_vector_type(4))) float f32x4;

// ---------------- zero counts ----------------
__global__ void zero_counts_kernel(int* __restrict__ counts) {
    int i = blockIdx.x * blockDim.x + threadIdx.x;   // 25000 threads, int4 each
    if (i < N_NODES / 4) ((int4*)counts)[i] = (int4){0, 0, 0, 0};
}

// ---------------- gemm body ----------
// One wave computes a 16-row x 128-col output stripe using 8 col-tiles of
// 16x16x32 f16 MFMA, K=128 in 4 steps. W pre-swizzled into B-fragment order
// in LDS so each B operand is a single ds_read_b128.
// A-fragment: lane holds A[m=lane&15][k=(lane>>4)*8+j]; C/D: col=lane&15,
// row=(lane>>4)*4+reg   [verified mapping, learn_hip m89]
__device__ __forceinline__ void gemm_body(
        const float* __restrict__ u_f, const float* __restrict__ v_f,
        const float* __restrict__ W, _Float16* __restrict__ node_f,
        _Float16* wfrag, int blockId, int nBlocks) {
    const int tid = threadIdx.x;

    // Build W fragments: element (t,s,lane,j) = W[s*32+(lane>>4)*8+j][t*16+(lane&15)]
    for (int f = tid * 64, end = tid * 64 + 64; f < end; ++f) {
        const int ts   = f >> 9;        // 0..31
        const int rem  = f & 511;
        const int ln   = rem >> 3;      // 0..63
        const int j    = rem & 7;
        const int t    = ts >> 2;
        const int s    = ts & 3;
        const int krow = s * 32 + (ln >> 4) * 8 + j;
        const int col  = t * 16 + (ln & 15);
        wfrag[f] = (_Float16)W[krow * DIM + col];
    }
    __syncthreads();

    const int lane = tid & 63;
    const int wave = tid >> 6;
    const int m    = lane & 15;
    const int quad = lane >> 4;
    const int n_wtiles = N_NODES / 16;  // 6250 (exact)

    for (int wt = blockId * 4 + wave; wt < n_wtiles; wt += nBlocks * 4) {
        const int row = wt * 16 + m;
        const float* src = (row < N_USERS) ? u_f + (size_t)row * DIM
                                           : v_f + (size_t)(row - N_USERS) * DIM;
        f32x4 acc[8];
        #pragma unroll
        for (int t = 0; t < 8; ++t) acc[t] = (f32x4){0.f, 0.f, 0.f, 0.f};

        #pragma unroll
        for (int s = 0; s < 4; ++s) {
            const float* ap = src + s * 32 + quad * 8;
            const float4 a0 = *(const float4*)ap;
            const float4 a1 = *(const float4*)(ap + 4);
            half8 af;
            af[0] = (_Float16)a0.x; af[1] = (_Float16)a0.y;
            af[2] = (_Float16)a0.z; af[3] = (_Float16)a0.w;
            af[4] = (_Float16)a1.x; af[5] = (_Float16)a1.y;
            af[6] = (_Float16)a1.z; af[7] = (_Float16)a1.w;
            #pragma unroll
            for (int t = 0; t < 8; ++t) {
                const half8 wf = *(const half8*)&wfrag[((t * 4 + s) * 64 + lane) * 8];
                acc[t] = __builtin_amdgcn_mfma_f32_16x16x32_f16(af, wf, acc[t], 0, 0, 0);
            }
        }

        const int base = wt * 16;
        #pragma unroll
        for (int t = 0; t < 8; ++t) {
            #pragma unroll
            for (int r = 0; r < 4; ++r) {
                const int orow = base + quad * 4 + r;
                node_f[(size_t)orow * DIM + t * 16 + m] = (_Float16)acc[t][r];
            }
        }
    }
}

// ---------------- fused: gemm (blocks 0..511) + bucket fill ----------------
__global__ __launch_bounds__(256) void fused_gemm_fill_kernel(
        const float* __restrict__ u_f, const float* __restrict__ v_f,
        const float* __restrict__ W, _Float16* __restrict__ node_f,
        const int* __restrict__ rows, const int* __restrict__ cols,
        const float* __restrict__ vals,
        int* __restrict__ counts, long long* __restrict__ buckets) {
    __shared__ _Float16 wfrag[32 * 64 * 8];   // 32 KB (unused by fill blocks)
    if (blockIdx.x < GEMM_BLOCKS) {
        gemm_body(u_f, v_f, W, node_f, wfrag, blockIdx.x, GEMM_BLOCKS);
        return;
    }
    const int e = (blockIdx.x - GEMM_BLOCKS) * 256 + threadIdx.x;  // < N_EDGES exact
    const int r = rows[e];
    const int slot = atomicAdd(&counts[r], 1);
    if (slot < CAP) {
        const long long packed =
            ((long long)__float_as_int(vals[e]) << 32) | (unsigned)cols[e];
        buckets[(size_t)r * CAP + slot] = packed;   // plain store: let L2 merge
    }
}

// standalone gemm for the fallback path
__global__ __launch_bounds__(256) void gemm_mfma_kernel(
        const float* __restrict__ u_f, const float* __restrict__ v_f,
        const float* __restrict__ W, _Float16* __restrict__ node_f) {
    __shared__ _Float16 wfrag[32 * 64 * 8];
    gemm_body(u_f, v_f, W, node_f, wfrag, blockIdx.x, gridDim.x);
}

// ---------------- gather v3: LDS-staged edge lists, deep unroll ------------
// Block = 4 waves = 4 rows. Bucket entries staged to LDS coalesced (2 KB),
// then the edge loop reads (col,val) via LDS *broadcast* (no shfl/bpermute).
// Pairwise lanes: lanes 0..31 = edge j, lanes 32..63 = edge j+1, 8 B/lane.
// 16-edge batches keep 8 independent row-loads in flight per wave.
__global__ __launch_bounds__(256) void gather_kernel(
        const _Float16* __restrict__ node_f, const int* __restrict__ counts,
        const long long* __restrict__ buckets, float* __restrict__ out) {
    __shared__ long long ebuf[4][CAP];     // 4 rows x 64 entries x 8 B
    __shared__ int scnt[4];
    const int tid  = threadIdx.x;
    const int row0 = blockIdx.x * 4;

    {   // stage: thread t loads entry (t>>6, t&63)
        const int r   = tid >> 6;
        const int s   = tid & 63;
        const int row = row0 + r;
        if (row < N_NODES) {
            if (s == 0) {
                int c = counts[row];
                scnt[r] = c > CAP ? CAP : c;
            }
            ebuf[r][s] = buckets[(size_t)row * CAP + s];  // coalesced; tail entries unused
        } else if (s == 0) {
            scnt[r] = 0;
        }
    }
    __syncthreads();

    const int wv   = tid >> 6;
    const int lane = tid & 63;
    const int row  = row0 + wv;
    if (row >= N_NODES) return;
    const int cnt = scnt[wv];
    const int pid = lane >> 5;          // which edge of the pair
    const int cl  = lane & 31;          // col-group: cols [cl*4, cl*4+4)
    const long long* eb = ebuf[wv];

    f32x4 acc = {0.f, 0.f, 0.f, 0.f};
    int j = 0;
    for (; j + 16 <= cnt; j += 16) {               // 8 pairs, 8 loads in flight
        int c[8]; float v[8]; half4 h[8];
        #pragma unroll
        for (int p = 0; p < 8; ++p) {
            const long long pk = eb[j + 2 * p + pid];   // LDS broadcast (2 addrs/wave)
            c[p] = (int)(unsigned)pk;
            v[p] = __int_as_float((int)(pk >> 32));
        }
        #pragma unroll
        for (int p = 0; p < 8; ++p)
            h[p] = *(const half4*)&node_f[(size_t)c[p] * DIM + cl * 4];
        #pragma unroll
        for (int p = 0; p < 8; ++p) {
            acc[0] += v[p] * (float)h[p][0];
            acc[1] += v[p] * (float)h[p][1];
            acc[2] += v[p] * (float)h[p][2];
            acc[3] += v[p] * (float)h[p][3];
        }
    }
    for (; j + 4 <= cnt; j += 4) {                 // 2 pairs
        int c[2]; float v[2]; half4 h[2];
        #pragma unroll
        for (int p = 0; p < 2; ++p) {
            const long long pk = eb[j + 2 * p + pid];
            c[p] = (int)(unsigned)pk;
            v[p] = __int_as_float((int)(pk >> 32));
        }
        #pragma unroll
        for (int p = 0; p < 2; ++p)
            h[p] = *(const half4*)&node_f[(size_t)c[p] * DIM + cl * 4];
        #pragma unroll
        for (int p = 0; p < 2; ++p) {
            acc[0] += v[p] * (float)h[p][0];
            acc[1] += v[p] * (float)h[p][1];
            acc[2] += v[p] * (float)h[p][2];
            acc[3] += v[p] * (float)h[p][3];
        }
    }
    if (j + 2 <= cnt) {                            // 1 pair
        const long long pk = eb[j + pid];
        const int   c = (int)(unsigned)pk;
        const float v = __int_as_float((int)(pk >> 32));
        const half4 h = *(const half4*)&node_f[(size_t)c * DIM + cl * 4];
        acc[0] += v * (float)h[0];
        acc[1] += v * (float)h[1];
        acc[2] += v * (float)h[2];
        acc[3] += v * (float)h[3];
        j += 2;
    }
    if (j < cnt) {                                 // odd edge: lower half only
        const long long pk = eb[j];
        const int   c  = (int)(unsigned)pk;
        const float vv = __int_as_float((int)(pk >> 32));
        const float v  = pid ? 0.f : vv;
        const half4 h = *(const half4*)&node_f[(size_t)c * DIM + cl * 4];
        acc[0] += v * (float)h[0];
        acc[1] += v * (float)h[1];
        acc[2] += v * (float)h[2];
        acc[3] += v * (float)h[3];
    }

    // merge the two pair-halves
    #pragma unroll
    for (int i = 0; i < 4; ++i) acc[i] += __shfl_xor(acc[i], 32, 64);

    if (pid == 0) {                                // lanes 0..31 store 16 B
        f32x4 r;
        r[0] = acc[0] > 0.f ? acc[0] : 0.f;        // fused relu
        r[1] = acc[1] > 0.f ? acc[1] : 0.f;
        r[2] = acc[2] > 0.f ? acc[2] : 0.f;
        r[3] = acc[3] > 0.f ? acc[3] : 0.f;
        // nt store: out is never re-read; keep 50MB out of L2
        __builtin_nontemporal_store(r, (f32x4*)&out[(size_t)row * DIM + cl * 4]);
    }
}

// ---------------- fallback path (small workspace): atomic scatter ----------
__global__ void zero_out_kernel(float* __restrict__ out) {
    int i = blockIdx.x * blockDim.x + threadIdx.x;
    int idx = i * 4;
    if (idx < N_NODES * DIM) {
        float4 z = {0.f, 0.f, 0.f, 0.f};
        *(float4*)&out[idx] = z;
    }
}

__global__ void scatter_kernel(const _Float16* __restrict__ node_f,
                               const int* __restrict__ rows, const int* __restrict__ cols,
                               const float* __restrict__ vals, float* __restrict__ out) {
    int t = blockIdx.x * blockDim.x + threadIdx.x;
    int e = t >> 5;             // 32 threads per edge, 4 elems each
    int part = t & 31;
    if (e >= N_EDGES) return;
    int r = rows[e], c = cols[e];
    float v = vals[e];
    const __half2 h0 = *(const __half2*)&node_f[(size_t)c * DIM + part * 4];
    const __half2 h1 = *(const __half2*)&node_f[(size_t)c * DIM + part * 4 + 2];
    const float2 f0 = __half22float2(h0);
    const float2 f1 = __half22float2(h1);
    float* dst = &out[(size_t)r * DIM + part * 4];
    unsafeAtomicAdd(dst + 0, v * f0.x);
    unsafeAtomicAdd(dst + 1, v * f0.y);
    unsafeAtomicAdd(dst + 2, v * f1.x);
    unsafeAtomicAdd(dst + 3, v * f1.y);
}

__global__ void relu_kernel(float* __restrict__ out) {
    int i = blockIdx.x * blockDim.x + threadIdx.x;
    int idx = i * 4;
    if (idx < N_NODES * DIM) {
        float4 v = *(float4*)&out[idx];
        v.x = v.x > 0.f ? v.x : 0.f;
        v.y = v.y > 0.f ? v.y : 0.f;
        v.z = v.z > 0.f ? v.z : 0.f;
        v.w = v.w > 0.f ? v.w : 0.f;
        *(float4*)&out[idx] = v;
    }
}

extern "C" void kernel_launch(void* const* d_in, const int* in_sizes, int n_in,
                              void* d_out, int out_size, void* d_ws, size_t ws_size,
                              hipStream_t stream) {
    const float* u_f  = (const float*)d_in[0];
    const float* v_f  = (const float*)d_in[1];
    const int*   rows = (const int*)d_in[2];
    const int*   cols = (const int*)d_in[3];
    const float* vals = (const float*)d_in[4];
    const float* W    = (const float*)d_in[5];
    float* out = (float*)d_out;

    char* ws = (char*)d_ws;
    const size_t nodef_bytes  = (size_t)N_NODES * DIM * 2;   // 25,600,000 (f16)
    const size_t counts_bytes = (size_t)N_NODES * 4;         //    400,000
    const size_t bucket_bytes = (size_t)N_NODES * CAP * 8;   // 51,200,000

    _Float16* node_f = (_Float16*)ws;
    int* counts = (int*)(ws + nodef_bytes);
    long long* buckets = (long long*)(ws + nodef_bytes + counts_bytes);

    if (ws_size >= nodef_bytes + counts_bytes + bucket_bytes) {
        zero_counts_kernel<<<(N_NODES / 4 + 255) / 256, 256, 0, stream>>>(counts);
        fused_gemm_fill_kernel<<<FUSED_GRID, 256, 0, stream>>>(
            u_f, v_f, W, node_f, rows, cols, vals, counts, buckets);
        gather_kernel<<<(N_NODES + 3) / 4, 256, 0, stream>>>(
            node_f, counts, buckets, out);
    } else {
        // fallback: atomic scatter
        gemm_mfma_kernel<<<512, 256, 0, stream>>>(u_f, v_f, W, node_f);
        zero_out_kernel<<<(N_NODES * DIM / 4 + 255) / 256, 256, 0, stream>>>(out);
        scatter_kernel<<<((size_t)N_EDGES * 32 + 255) / 256, 256, 0, stream>>>(
            node_f, rows, cols, vals, out);
        relu_kernel<<<(N_NODES * DIM / 4 + 255) / 256, 256, 0, stream>>>(out);
    }
}

// Round 9
// 270.800 us; speedup vs baseline: 1.0918x; 1.0159x over previous
//
#include <hip/hip_runtime.h>
#include <hip/hip_bf16.h>
#include <hip/hip_fp16.h>

// Problem constants (from reference file)
#define N_USERS 50000
#define N_NODES 100000
#define N_EDGES 1600000
#define DIM 128
#define CAP 64            // per-row bucket capacity (max degree ~45 for Poisson(16))

// fused kernel (R6 shape — best measured): blocks 0..511 gemm w/ LDS wfrag,
// blocks 512.. bucket fill at 1 edge/thread. R5 (4 edges/thread) and R7
// (no-LDS gemm + high occupancy) both regressed: fill is memory-side
// atomic/line-throughput bound, gemm needs its registers.
#define GEMM_BLOCKS 512
#define FILL_BLOCKS (N_EDGES / 256)            // 6250, exact
#define FUSED_GRID (GEMM_BLOCKS + FILL_BLOCKS)

typedef __attribute__((ext_vector_type(8))) _Float16 half8;
typedef __attribute__((ext_vector_type(4))) _Float16 half4;
typedef __attribute__((ext_vector_type(4))) float f32x4;

// ---------------- zero counts ----------------
__global__ void zero_counts_kernel(int* __restrict__ counts) {
    int i = blockIdx.x * blockDim.x + threadIdx.x;   // 25000 threads, int4 each
    if (i < N_NODES / 4) ((int4*)counts)[i] = (int4){0, 0, 0, 0};
}

// ---------------- gemm body ----------
// One wave computes a 16-row x 128-col output stripe using 8 col-tiles of
// 16x16x32 f16 MFMA, K=128 in 4 steps. W pre-swizzled into B-fragment order
// in LDS so each B operand is a single ds_read_b128.
// A-fragment: lane holds A[m=lane&15][k=(lane>>4)*8+j]; C/D: col=lane&15,
// row=(lane>>4)*4+reg   [verified mapping, learn_hip m89]
__device__ __forceinline__ void gemm_body(
        const float* __restrict__ u_f, const float* __restrict__ v_f,
        const float* __restrict__ W, _Float16* __restrict__ node_f,
        _Float16* wfrag, int blockId, int nBlocks) {
    const int tid = threadIdx.x;

    // Build W fragments: element (t,s,lane,j) = W[s*32+(lane>>4)*8+j][t*16+(lane&15)]
    for (int f = tid * 64, end = tid * 64 + 64; f < end; ++f) {
        const int ts   = f >> 9;        // 0..31
        const int rem  = f & 511;
        const int ln   = rem >> 3;      // 0..63
        const int j    = rem & 7;
        const int t    = ts >> 2;
        const int s    = ts & 3;
        const int krow = s * 32 + (ln >> 4) * 8 + j;
        const int col  = t * 16 + (ln & 15);
        wfrag[f] = (_Float16)W[krow * DIM + col];
    }
    __syncthreads();

    const int lane = tid & 63;
    const int wave = tid >> 6;
    const int m    = lane & 15;
    const int quad = lane >> 4;
    const int n_wtiles = N_NODES / 16;  // 6250 (exact)

    for (int wt = blockId * 4 + wave; wt < n_wtiles; wt += nBlocks * 4) {
        const int row = wt * 16 + m;
        const float* src = (row < N_USERS) ? u_f + (size_t)row * DIM
                                           : v_f + (size_t)(row - N_USERS) * DIM;
        f32x4 acc[8];
        #pragma unroll
        for (int t = 0; t < 8; ++t) acc[t] = (f32x4){0.f, 0.f, 0.f, 0.f};

        #pragma unroll
        for (int s = 0; s < 4; ++s) {
            const float* ap = src + s * 32 + quad * 8;
            const float4 a0 = *(const float4*)ap;
            const float4 a1 = *(const float4*)(ap + 4);
            half8 af;
            af[0] = (_Float16)a0.x; af[1] = (_Float16)a0.y;
            af[2] = (_Float16)a0.z; af[3] = (_Float16)a0.w;
            af[4] = (_Float16)a1.x; af[5] = (_Float16)a1.y;
            af[6] = (_Float16)a1.z; af[7] = (_Float16)a1.w;
            #pragma unroll
            for (int t = 0; t < 8; ++t) {
                const half8 wf = *(const half8*)&wfrag[((t * 4 + s) * 64 + lane) * 8];
                acc[t] = __builtin_amdgcn_mfma_f32_16x16x32_f16(af, wf, acc[t], 0, 0, 0);
            }
        }

        const int base = wt * 16;
        #pragma unroll
        for (int t = 0; t < 8; ++t) {
            #pragma unroll
            for (int r = 0; r < 4; ++r) {
                const int orow = base + quad * 4 + r;
                node_f[(size_t)orow * DIM + t * 16 + m] = (_Float16)acc[t][r];
            }
        }
    }
}

// ---------------- fused: gemm (blocks 0..511) + bucket fill ----------------
__global__ __launch_bounds__(256) void fused_gemm_fill_kernel(
        const float* __restrict__ u_f, const float* __restrict__ v_f,
        const float* __restrict__ W, _Float16* __restrict__ node_f,
        const int* __restrict__ rows, const int* __restrict__ cols,
        const float* __restrict__ vals,
        int* __restrict__ counts, long long* __restrict__ buckets) {
    __shared__ _Float16 wfrag[32 * 64 * 8];   // 32 KB (unused by fill blocks)
    if (blockIdx.x < GEMM_BLOCKS) {
        gemm_body(u_f, v_f, W, node_f, wfrag, blockIdx.x, GEMM_BLOCKS);
        return;
    }
    const int e = (blockIdx.x - GEMM_BLOCKS) * 256 + threadIdx.x;  // < N_EDGES exact
    const int r = rows[e];
    const int slot = atomicAdd(&counts[r], 1);
    if (slot < CAP) {
        const long long packed =
            ((long long)__float_as_int(vals[e]) << 32) | (unsigned)cols[e];
        buckets[(size_t)r * CAP + slot] = packed;   // plain store: let L2 merge
    }
}

// standalone gemm for the fallback path
__global__ __launch_bounds__(256) void gemm_mfma_kernel(
        const float* __restrict__ u_f, const float* __restrict__ v_f,
        const float* __restrict__ W, _Float16* __restrict__ node_f) {
    __shared__ _Float16 wfrag[32 * 64 * 8];
    gemm_body(u_f, v_f, W, node_f, wfrag, blockIdx.x, gridDim.x);
}

// ---------------- gather v4: LDS-staged, 16-edge-padded batches ------------
// Block = 4 waves = 4 rows (grid 25000, exact). Bucket entries staged to LDS
// coalesced; slots >= cnt are zeroed (col=0,val=0 dummies -> read hot row 0,
// add 0). Edge loop runs ONLY full 16-edge batches (8 pairs, 8 independent
// 8B row-loads in flight): cnt<=16 rows take exactly ONE memory round
// instead of up to 5 dependent sub-batches (the R8 serial-tail problem).
__global__ __launch_bounds__(256) void gather_kernel(
        const _Float16* __restrict__ node_f, const int* __restrict__ counts,
        const long long* __restrict__ buckets, float* __restrict__ out) {
    __shared__ long long ebuf[4][CAP];     // 4 rows x 64 entries x 8 B
    const int tid  = threadIdx.x;
    const int row0 = blockIdx.x * 4;
    const int r    = tid >> 6;             // wave id == staged row id
    const int s    = tid & 63;
    const int row  = row0 + r;

    int cnt = counts[row];                 // same addr across the wave -> hot
    if (cnt > CAP) cnt = CAP;
    {   // stage: zero-pad beyond cnt (never deref poisoned slots)
        long long pk = 0;
        if (s < cnt) pk = buckets[(size_t)row * CAP + s];   // coalesced
        ebuf[r][s] = pk;
    }
    __syncthreads();

    const int lane = s;
    const int pid  = lane >> 5;            // which edge of the pair
    const int cl   = lane & 31;            // col-group: cols [cl*4, cl*4+4)
    const long long* eb = ebuf[r];
    const int rcnt = (cnt + 15) & ~15;     // padded trip count

    f32x4 acc = {0.f, 0.f, 0.f, 0.f};
    for (int j = 0; j < rcnt; j += 16) {   // full batches only: 8 loads in flight
        int c[8]; float v[8]; half4 h[8];
        #pragma unroll
        for (int p = 0; p < 8; ++p) {
            const long long pk = eb[j + 2 * p + pid];   // LDS broadcast
            c[p] = (int)(unsigned)pk;
            v[p] = __int_as_float((int)(pk >> 32));
        }
        #pragma unroll
        for (int p = 0; p < 8; ++p)
            h[p] = *(const half4*)&node_f[(size_t)c[p] * DIM + cl * 4];
        #pragma unroll
        for (int p = 0; p < 8; ++p) {
            acc[0] += v[p] * (float)h[p][0];
            acc[1] += v[p] * (float)h[p][1];
            acc[2] += v[p] * (float)h[p][2];
            acc[3] += v[p] * (float)h[p][3];
        }
    }

    // merge the two pair-halves
    #pragma unroll
    for (int i = 0; i < 4; ++i) acc[i] += __shfl_xor(acc[i], 32, 64);

    if (pid == 0) {                        // lanes 0..31 store 16 B
        f32x4 o;
        o[0] = acc[0] > 0.f ? acc[0] : 0.f;   // fused relu
        o[1] = acc[1] > 0.f ? acc[1] : 0.f;
        o[2] = acc[2] > 0.f ? acc[2] : 0.f;
        o[3] = acc[3] > 0.f ? acc[3] : 0.f;
        // nt store: out is never re-read; keep 50MB out of L2
        __builtin_nontemporal_store(o, (f32x4*)&out[(size_t)row * DIM + cl * 4]);
    }
}

// ---------------- fallback path (small workspace): atomic scatter ----------
__global__ void zero_out_kernel(float* __restrict__ out) {
    int i = blockIdx.x * blockDim.x + threadIdx.x;
    int idx = i * 4;
    if (idx < N_NODES * DIM) {
        float4 z = {0.f, 0.f, 0.f, 0.f};
        *(float4*)&out[idx] = z;
    }
}

__global__ void scatter_kernel(const _Float16* __restrict__ node_f,
                               const int* __restrict__ rows, const int* __restrict__ cols,
                               const float* __restrict__ vals, float* __restrict__ out) {
    int t = blockIdx.x * blockDim.x + threadIdx.x;
    int e = t >> 5;             // 32 threads per edge, 4 elems each
    int part = t & 31;
    if (e >= N_EDGES) return;
    int r = rows[e], c = cols[e];
    float v = vals[e];
    const __half2 h0 = *(const __half2*)&node_f[(size_t)c * DIM + part * 4];
    const __half2 h1 = *(const __half2*)&node_f[(size_t)c * DIM + part * 4 + 2];
    const float2 f0 = __half22float2(h0);
    const float2 f1 = __half22float2(h1);
    float* dst = &out[(size_t)r * DIM + part * 4];
    unsafeAtomicAdd(dst + 0, v * f0.x);
    unsafeAtomicAdd(dst + 1, v * f0.y);
    unsafeAtomicAdd(dst + 2, v * f1.x);
    unsafeAtomicAdd(dst + 3, v * f1.y);
}

__global__ void relu_kernel(float* __restrict__ out) {
    int i = blockIdx.x * blockDim.x + threadIdx.x;
    int idx = i * 4;
    if (idx < N_NODES * DIM) {
        float4 v = *(float4*)&out[idx];
        v.x = v.x > 0.f ? v.x : 0.f;
        v.y = v.y > 0.f ? v.y : 0.f;
        v.z = v.z > 0.f ? v.z : 0.f;
        v.w = v.w > 0.f ? v.w : 0.f;
        *(float4*)&out[idx] = v;
    }
}

extern "C" void kernel_launch(void* const* d_in, const int* in_sizes, int n_in,
                              void* d_out, int out_size, void* d_ws, size_t ws_size,
                              hipStream_t stream) {
    const float* u_f  = (const float*)d_in[0];
    const float* v_f  = (const float*)d_in[1];
    const int*   rows = (const int*)d_in[2];
    const int*   cols = (const int*)d_in[3];
    const float* vals = (const float*)d_in[4];
    const float* W    = (const float*)d_in[5];
    float* out = (float*)d_out;

    char* ws = (char*)d_ws;
    const size_t nodef_bytes  = (size_t)N_NODES * DIM * 2;   // 25,600,000 (f16)
    const size_t counts_bytes = (size_t)N_NODES * 4;         //    400,000
    const size_t bucket_bytes = (size_t)N_NODES * CAP * 8;   // 51,200,000

    _Float16* node_f = (_Float16*)ws;
    int* counts = (int*)(ws + nodef_bytes);
    long long* buckets = (long long*)(ws + nodef_bytes + counts_bytes);

    if (ws_size >= nodef_bytes + counts_bytes + bucket_bytes) {
        zero_counts_kernel<<<(N_NODES / 4 + 255) / 256, 256, 0, stream>>>(counts);
        fused_gemm_fill_kernel<<<FUSED_GRID, 256, 0, stream>>>(
            u_f, v_f, W, node_f, rows, cols, vals, counts, buckets);
        gather_kernel<<<N_NODES / 4, 256, 0, stream>>>(
            node_f, counts, buckets, out);
    } else {
        // fallback: atomic scatter
        gemm_mfma_kernel<<<512, 256, 0, stream>>>(u_f, v_f, W, node_f);
        zero_out_kernel<<<(N_NODES * DIM / 4 + 255) / 256, 256, 0, stream>>>(out);
        scatter_kernel<<<((size_t)N_EDGES * 32 + 255) / 256, 256, 0, stream>>>(
            node_f, rows, cols, vals, out);
        relu_kernel<<<(N_NODES * DIM / 4 + 255) / 256, 256, 0, stream>>>(out);
    }
}